// Round 9
// baseline (564.078 us; speedup 1.0000x reference)
//
#include <hip/hip_runtime.h>

// Qwen3 MoE experts: per-expert SwiGLU MLP.
//   gate = rin @ gate_proj^T ; up = rin @ up_proj^T
//   hidden = silu(gate) * up ; out = hidden @ down_proj^T
// E=32, T=512, H=2048, I=768. f32 inputs; bf16 MFMA, f32 accum.
//
// R8: W-in-registers. Weight streams (402 MB > L3) are the HBM-missing,
//     latency-exposed part. Staging them through LDS caps prefetch depth at
//     LDS size. Instead: per-wave W fragments global->VGPR, double-buffered
//     by loop parity -> prefetch distance 2 full iters at FULL tile size.
//     A (L2-warm, reused 12x) reg-staged as bf16 into a 16 KB LDS dbuf.
//     No global_load_lds, no manual vmcnt: all loads compiler-tracked.
//     Raw s_barrier + lgkmcnt(0) only (no vmcnt(0) drain at barriers).
//     gate+up fused (one A read, silu fused epilogue). ws: hidden 24 MB.

#define NE 32
#define NT 512
#define NH 2048
#define NI 768
#define NTI ((size_t)NE * NT * NI)

typedef short        short8  __attribute__((ext_vector_type(8)));
typedef float        floatx4 __attribute__((ext_vector_type(4)));
typedef unsigned int uintx4  __attribute__((ext_vector_type(4)));
typedef __attribute__((address_space(1))) const unsigned int g_u32;
typedef __attribute__((address_space(3))) unsigned int l_u32;

__device__ __forceinline__ void gl_lds16(const void* g, void* l) {
    __builtin_amdgcn_global_load_lds((g_u32*)g, (l_u32*)l, 16, 0, 0);
}

__device__ __forceinline__ unsigned int cvt_pk_bf16(float lo, float hi) {
    unsigned int r;
    asm("v_cvt_pk_bf16_f32 %0, %1, %2" : "=v"(r) : "v"(lo), "v"(hi));
    return r;
}

__device__ __forceinline__ short8 frag8(floatx4 x0, floatx4 x1) {
    union { unsigned int u[4]; short8 s; } t;
    t.u[0] = cvt_pk_bf16(x0[0], x0[1]);
    t.u[1] = cvt_pk_bf16(x0[2], x0[3]);
    t.u[2] = cvt_pk_bf16(x1[0], x1[1]);
    t.u[3] = cvt_pk_bf16(x1[2], x1[3]);
    return t.s;
}

__device__ __forceinline__ uintx4 pack8(floatx4 x0, floatx4 x1) {
    uintx4 u;
    u[0] = cvt_pk_bf16(x0[0], x0[1]);
    u[1] = cvt_pk_bf16(x0[2], x0[3]);
    u[2] = cvt_pk_bf16(x1[0], x1[1]);
    u[3] = cvt_pk_bf16(x1[2], x1[3]);
    return u;
}

__device__ __forceinline__ ushort f2bf(float f) {
    union { float f; unsigned int u; } v; v.f = f;
    unsigned int r = v.u + 0x7fffu + ((v.u >> 16) & 1u);
    return (ushort)(r >> 16);
}

// ---------------------------------------------------------------------------
// Kernel 1: fused gate+up + SwiGLU -> hidden(bf16).
// BM=128(T) x BN_I=64, BK=32 over H; 4 waves (2x2): wave = 64 T x 32 I,
// 4x2 frags per GEMM (gate AND up share A). W frags live in registers.
// LDS: A bf16 [2][128][32] = 16 KB only.
// ---------------------------------------------------------------------------
__global__ __launch_bounds__(256, 2) void moe_gateup(
    const float* __restrict__ rin, const float* __restrict__ gate,
    const float* __restrict__ up, ushort* __restrict__ hidden)
{
    __shared__ ushort As[2][128][32];

    // XCD-bijective swizzle: 1536 blocks, chunk 192
    const int bid = blockIdx.x;
    const int wg  = (bid & 7) * 192 + (bid >> 3);
    const int e   = wg / 48;
    const int r48 = wg % 48;
    const int ti  = r48 % 12;   // I tile of 64
    const int tm  = r48 / 12;   // T tile of 128

    const int tid  = threadIdx.x;
    const int lane = tid & 63;
    const int wave = tid >> 6;
    const int wr = wave >> 1, wc = wave & 1;

    const float* Ab = rin  + (size_t)e * NT * NH + (size_t)(tm * 128) * NH;
    const float* Gb = gate + (size_t)e * NI * NH + (size_t)(ti * 64) * NH;
    const float* Ub = up   + (size_t)e * NI * NH + (size_t)(ti * 64) * NH;

    const int frow = lane & 15;
    const int h    = lane >> 4;          // k-group 0..3 (8 f32 each)

    // per-lane W row pointers (n = 0,1), at this lane's k-group
    const float* gp0 = Gb + (size_t)(wc * 32 + frow) * NH + h * 8;
    const float* gp1 = gp0 + (size_t)16 * NH;
    const float* up0 = Ub + (size_t)(wc * 32 + frow) * NH + h * 8;
    const float* up1 = up0 + (size_t)16 * NH;

    // A staging map: thread -> row t>>1, f32 col half (t&1)*16 (16 f32).
    const int a_row  = tid >> 1;
    const int a_half = (tid & 1) * 16;
    const float* Asrc = Ab + (size_t)a_row * NH + a_half;
    const int wp0 = (((tid & 1) * 2)     + (a_row >> 1)) & 3;  // phys chunk
    const int wp1 = (((tid & 1) * 2) + 1 + (a_row >> 1)) & 3;

    floatx4 accg[4][2], accu[4][2];
    #pragma unroll
    for (int m = 0; m < 4; ++m)
        #pragma unroll
        for (int n = 0; n < 2; ++n) {
            accg[m][n] = (floatx4)0.f;
            accu[m][n] = (floatx4)0.f;
        }

    const int KT = NH / 32;   // 64

    // W prefetch registers: [parity][n][half]
    floatx4 pg0[2][2], pg1[2][2], pu0[2][2], pu1[2][2];
    floatx4 ra[4];            // A staging registers (16 f32)

#define ISSUE_W(kt, P) do {                                                  \
        const int k_ = (kt) * 32;                                            \
        pg0[P][0] = *(const floatx4*)(gp0 + k_);                             \
        pg0[P][1] = *(const floatx4*)(gp0 + k_ + 4);                         \
        pg1[P][0] = *(const floatx4*)(gp1 + k_);                             \
        pg1[P][1] = *(const floatx4*)(gp1 + k_ + 4);                         \
        pu0[P][0] = *(const floatx4*)(up0 + k_);                             \
        pu0[P][1] = *(const floatx4*)(up0 + k_ + 4);                         \
        pu1[P][0] = *(const floatx4*)(up1 + k_);                             \
        pu1[P][1] = *(const floatx4*)(up1 + k_ + 4);                         \
    } while (0)

#define ISSUE_A(kt) do {                                                     \
        const int k_ = (kt) * 32;                                            \
        ra[0] = *(const floatx4*)(Asrc + k_);                                \
        ra[1] = *(const floatx4*)(Asrc + k_ + 4);                            \
        ra[2] = *(const floatx4*)(Asrc + k_ + 8);                            \
        ra[3] = *(const floatx4*)(Asrc + k_ + 12);                           \
    } while (0)

#define STAGE_A(b) do {                                                      \
        *(uintx4*)&As[b][a_row][wp0 * 8] = pack8(ra[0], ra[1]);              \
        *(uintx4*)&As[b][a_row][wp1 * 8] = pack8(ra[2], ra[3]);              \
    } while (0)

#define BODY(kt, P) do {                                                     \
        short8 gf0 = frag8(pg0[P][0], pg0[P][1]);                            \
        short8 gf1 = frag8(pg1[P][0], pg1[P][1]);                            \
        short8 uf0 = frag8(pu0[P][0], pu0[P][1]);                            \
        short8 uf1 = frag8(pu1[P][0], pu1[P][1]);                            \
        if ((kt) + 2 < KT) ISSUE_W((kt) + 2, P);                             \
        short8 af[4];                                                        \
        _Pragma("unroll")                                                    \
        for (int m = 0; m < 4; ++m) {                                        \
            const int R = wr * 64 + m * 16 + frow;                           \
            const int p = (h + (R >> 1)) & 3;                                \
            af[m] = *(const short8*)&As[P][R][p * 8];                        \
        }                                                                    \
        _Pragma("unroll")                                                    \
        for (int m = 0; m < 4; ++m) {                                        \
            accg[m][0] = __builtin_amdgcn_mfma_f32_16x16x32_bf16(            \
                af[m], gf0, accg[m][0], 0, 0, 0);                            \
            accg[m][1] = __builtin_amdgcn_mfma_f32_16x16x32_bf16(            \
                af[m], gf1, accg[m][1], 0, 0, 0);                            \
            accu[m][0] = __builtin_amdgcn_mfma_f32_16x16x32_bf16(            \
                af[m], uf0, accu[m][0], 0, 0, 0);                            \
            accu[m][1] = __builtin_amdgcn_mfma_f32_16x16x32_bf16(            \
                af[m], uf1, accu[m][1], 0, 0, 0);                            \
        }                                                                    \
        if ((kt) + 1 < KT) {                                                 \
            STAGE_A(P ^ 1);                                                  \
            if ((kt) + 2 < KT) ISSUE_A((kt) + 2);                            \
            asm volatile("s_waitcnt lgkmcnt(0)" ::: "memory");               \
            __builtin_amdgcn_sched_barrier(0);                               \
            __builtin_amdgcn_s_barrier();                                    \
        }                                                                    \
    } while (0)

    // prologue: W tiles 0,1 in flight; A(0) staged; A(1) in flight
    ISSUE_W(0, 0);
    ISSUE_W(1, 1);
    ISSUE_A(0);
    STAGE_A(0);
    ISSUE_A(1);
    asm volatile("s_waitcnt lgkmcnt(0)" ::: "memory");
    __builtin_amdgcn_sched_barrier(0);
    __builtin_amdgcn_s_barrier();

    for (int kt = 0; kt < KT; kt += 2) {
        BODY(kt, 0);
        BODY(kt + 1, 1);
    }
#undef BODY
#undef ISSUE_W
#undef ISSUE_A
#undef STAGE_A

    // Epilogue: silu(g)*u -> bf16. C/D: col=lane&15, row=(lane>>4)*4+reg.
    const int ccol  = lane & 15;
    const int crow0 = (lane >> 4) * 4;
    const size_t hbase = ((size_t)e * NT + (size_t)tm * 128) * NI + ti * 64;
    #pragma unroll
    for (int m = 0; m < 4; ++m)
        #pragma unroll
        for (int n = 0; n < 2; ++n)
            #pragma unroll
            for (int j = 0; j < 4; ++j) {
                const float g = accg[m][n][j];
                const float u = accu[m][n][j];
                const float hh = (g / (1.f + __expf(-g))) * u;
                const int row = wr * 64 + m * 16 + crow0 + j;
                const int col = wc * 32 + n * 16 + ccol;
                hidden[hbase + (size_t)row * NI + col] = f2bf(hh);
            }
}

// ---------------------------------------------------------------------------
// Kernel 2: down projection (unchanged, proven ~715 TF effective).
// ---------------------------------------------------------------------------
__global__ __launch_bounds__(256, 2) void moe_down(
    const ushort* __restrict__ hidden, const float* __restrict__ down,
    float* __restrict__ out)
{
    __shared__ ushort As[2][128][32];
    __shared__ float  Bs[2][128][32];

    const int bid = blockIdx.x;
    const int wg  = (bid & 7) * (2048 / 8) + (bid >> 3);
    const int e   = wg >> 6;
    const int rem = wg & 63;
    const int tn  = rem & 15;
    const int tm  = rem >> 4;

    const int tid  = threadIdx.x;
    const int lane = tid & 63;
    const int wave = tid >> 6;
    const int wr = wave >> 1, wc = wave & 1;

    const ushort* Ab = hidden + ((size_t)e * NT + (size_t)tm * 128) * NI;
    const float*  Bb = down + (size_t)e * NH * NI + (size_t)(tn * 128) * NI;

    floatx4 acc[4][4];
    #pragma unroll
    for (int m = 0; m < 4; ++m)
        #pragma unroll
        for (int n = 0; n < 4; ++n) acc[m][n] = (floatx4)0.f;

    const int frow = lane & 15;
    const int h    = lane >> 4;
    const int ca   = h ^ (frow & 3);
    const int rb   = frow & 7;
    const int c0   = (2 * h) ^ rb;
    const int c1   = (2 * h + 1) ^ rb;
    const int KT = NI / 32;

#define STAGE_DN(kt, b) do {                                                 \
        const int k0_ = (kt) * 32;                                           \
        _Pragma("unroll")                                                    \
        for (int i = 0; i < 2; ++i) {                                        \
            const int g_ = wave * 2 + i;                                     \
            const int r_ = g_ * 16 + (lane >> 2);                            \
            const int cs_ = (lane & 3) ^ (r_ & 3);                           \
            gl_lds16(Ab + (size_t)r_ * NI + k0_ + cs_ * 8, &As[b][g_ * 16][0]); \
        }                                                                    \
        _Pragma("unroll")                                                    \
        for (int i = 0; i < 4; ++i) {                                        \
            const int g_ = wave * 4 + i;                                     \
            const int r_ = g_ * 8 + (lane >> 3);                             \
            const int cs_ = (lane & 7) ^ (r_ & 7);                           \
            gl_lds16(Bb + (size_t)r_ * NI + k0_ + cs_ * 4, &Bs[b][g_ * 8][0]); \
        }                                                                    \
    } while (0)

    STAGE_DN(0, 0);

    for (int kt = 0; kt < KT; ++kt) {
        const int cur = kt & 1;
        if (kt + 1 < KT) {
            STAGE_DN(kt + 1, cur ^ 1);
            asm volatile("s_waitcnt vmcnt(6)" ::: "memory");
        } else {
            asm volatile("s_waitcnt vmcnt(0)" ::: "memory");
        }
        __builtin_amdgcn_s_barrier();

        short8 af[4], bf[4];
        #pragma unroll
        for (int m = 0; m < 4; ++m) {
            const int R = wr * 64 + m * 16 + frow;
            af[m] = *(const short8*)&As[cur][R][ca * 8];
        }
        #pragma unroll
        for (int n = 0; n < 4; ++n) {
            const int R = wc * 64 + n * 16 + frow;
            bf[n] = frag8(*(const floatx4*)&Bs[cur][R][c0 * 4],
                          *(const floatx4*)&Bs[cur][R][c1 * 4]);
        }
        #pragma unroll
        for (int m = 0; m < 4; ++m)
            #pragma unroll
            for (int n = 0; n < 4; ++n)
                acc[m][n] = __builtin_amdgcn_mfma_f32_16x16x32_bf16(
                    af[m], bf[n], acc[m][n], 0, 0, 0);

        asm volatile("s_waitcnt lgkmcnt(0)" ::: "memory");
        __builtin_amdgcn_sched_barrier(0);
        __builtin_amdgcn_s_barrier();
    }
#undef STAGE_DN

    const int ccol  = lane & 15;
    const int crow0 = (lane >> 4) * 4;
    float* Ob = out + ((size_t)e * NT + (size_t)tm * 128) * NH + tn * 128;
    #pragma unroll
    for (int m = 0; m < 4; ++m)
        #pragma unroll
        for (int n = 0; n < 4; ++n)
            #pragma unroll
            for (int j = 0; j < 4; ++j) {
                const int row = wr * 64 + m * 16 + crow0 + j;
                const int col = wc * 64 + n * 16 + ccol;
                Ob[(size_t)row * NH + col] = acc[m][n][j];
            }
}

extern "C" void kernel_launch(void* const* d_in, const int* in_sizes, int n_in,
                              void* d_out, int out_size, void* d_ws, size_t ws_size,
                              hipStream_t stream) {
    const float* rin  = (const float*)d_in[0];
    const float* gate = (const float*)d_in[1];
    const float* up   = (const float*)d_in[2];
    const float* down = (const float*)d_in[3];
    float* out = (float*)d_out;
    ushort* hidden = (ushort*)d_ws;   // [E,T,I] bf16, 24 MB

    dim3 blk(256);
    moe_gateup<<<dim3(1536), blk, 0, stream>>>(rin, gate, up, hidden);
    moe_down<<<dim3(2048), blk, 0, stream>>>(hidden, down, out);
}

// Round 10
// 373.046 us; speedup vs baseline: 1.5121x; 1.5121x over previous
//
#include <hip/hip_runtime.h>

// Qwen3 MoE experts: per-expert SwiGLU MLP.
//   gate = rin @ gate_proj^T ; up = rin @ up_proj^T
//   hidden = silu(gate) * up ; out = hidden @ down_proj^T
// E=32, T=512, H=2048, I=768. f32 inputs; bf16 MFMA, f32 accum.
//
// R9: staged-VOLUME reduction. 9-round ablation shows gateup saturates
//     ~8-9 TB/s aggregate staging BW under every structure; volume is the
//     lever. Fused 256x96 tile: 56 MB/expert staged (vs 128^2's 72).
//     512 thr / 8 waves (acc 96 AGPR), all-f32 gl_lds dbuf 112 KB
//     (1 block/CU but 2 waves/SIMD), counted vmcnt(7), 512 blocks = 2
//     even rounds. Staging geometry = R6's (best measured: 9.4 TB/s).
// ws: hidden [E,T,I] bf16 = 24 MB.

#define NE 32
#define NT 512
#define NH 2048
#define NI 768

typedef short        short8  __attribute__((ext_vector_type(8)));
typedef float        floatx4 __attribute__((ext_vector_type(4)));
typedef __attribute__((address_space(1))) const unsigned int g_u32;
typedef __attribute__((address_space(3))) unsigned int l_u32;

__device__ __forceinline__ void gl_lds16(const void* g, void* l) {
    __builtin_amdgcn_global_load_lds((g_u32*)g, (l_u32*)l, 16, 0, 0);
}

__device__ __forceinline__ unsigned int cvt_pk_bf16(float lo, float hi) {
    unsigned int r;
    asm("v_cvt_pk_bf16_f32 %0, %1, %2" : "=v"(r) : "v"(lo), "v"(hi));
    return r;
}

__device__ __forceinline__ short8 frag8(floatx4 x0, floatx4 x1) {
    union { unsigned int u[4]; short8 s; } t;
    t.u[0] = cvt_pk_bf16(x0[0], x0[1]);
    t.u[1] = cvt_pk_bf16(x0[2], x0[3]);
    t.u[2] = cvt_pk_bf16(x1[0], x1[1]);
    t.u[3] = cvt_pk_bf16(x1[2], x1[3]);
    return t.s;
}

__device__ __forceinline__ ushort f2bf(float f) {
    union { float f; unsigned int u; } v; v.f = f;
    unsigned int r = v.u + 0x7fffu + ((v.u >> 16) & 1u);
    return (ushort)(r >> 16);
}

// ---------------------------------------------------------------------------
// Kernel 1: fused gate+up + SwiGLU -> hidden(bf16).
// BM=256(T) x BN=96(I), BK=32 over H. 512 thr = 8 waves, grid 4(row)x2(col):
// wave tile 64(T) x 48(I), 4x3 frags of 16x16 per GEMM, acc 96 AGPR.
// LDS: f32 dbuf  A[2][256][32] + G,U[2][96][32] = 112 KB (1 block/CU).
// Staging: gl_lds(16B), source chunk-XOR swizzle (rule #21), vmcnt(7).
// ---------------------------------------------------------------------------
__global__ __launch_bounds__(512, 1) void moe_gateup(
    const float* __restrict__ rin, const float* __restrict__ gate,
    const float* __restrict__ up, ushort* __restrict__ hidden)
{
    __shared__ float As[2][256][32];
    __shared__ float Gs[2][96][32];
    __shared__ float Us[2][96][32];

    // XCD-bijective swizzle: 512 blocks, chunk 64
    const int bid = blockIdx.x;
    const int wg  = (bid & 7) * 64 + (bid >> 3);
    const int e   = wg >> 4;
    const int rem = wg & 15;
    const int tm  = rem >> 3;   // T tile of 256: 0..1
    const int ti  = rem & 7;    // I tile of 96:  0..7

    const int tid  = threadIdx.x;
    const int lane = tid & 63;
    const int wave = tid >> 6;          // 0..7
    const int wr = wave >> 1;           // 0..3 (T band of 64)
    const int wc = wave & 1;            // 0..1 (I band of 48)

    const float* Ab = rin  + (size_t)e * NT * NH + (size_t)(tm * 256) * NH;
    const float* Gb = gate + (size_t)e * NI * NH + (size_t)(ti * 96) * NH;
    const float* Ub = up   + (size_t)e * NI * NH + (size_t)(ti * 96) * NH;

    floatx4 accg[4][3], accu[4][3];
    #pragma unroll
    for (int m = 0; m < 4; ++m)
        #pragma unroll
        for (int n = 0; n < 3; ++n) {
            accg[m][n] = (floatx4)0.f;
            accu[m][n] = (floatx4)0.f;
        }

    const int frow = lane & 15;
    const int h    = lane >> 4;
    const int KT = NH / 32;   // 64

    // per-wave W source/dest for the 3 G-or-U staging insts
    const float* Wsrc = (wave < 4) ? Gb : Ub;
    const int    wband = (wave & 3) * 24;   // rows [wband, wband+24)

    // 7 gl_lds per wave per stage: 4 x A (rows wave*32..+32),
    // 3 x G-or-U (rows wband..+24). Each inst = 8 rows x 128 B.
#define STAGE(kt, b) do {                                                    \
        const int k0_ = (kt) * 32;                                           \
        _Pragma("unroll")                                                    \
        for (int i = 0; i < 4; ++i) {                                        \
            const int g_ = wave * 4 + i;                                     \
            const int r_ = g_ * 8 + (lane >> 3);                             \
            const int cs_ = (lane & 7) ^ (r_ & 7);                           \
            gl_lds16(Ab + (size_t)r_ * NH + k0_ + cs_ * 4, &As[b][g_ * 8][0]); \
        }                                                                    \
        float* wdst_ = (wave < 4) ? &Gs[b][wband][0] : &Us[b][wband][0];     \
        _Pragma("unroll")                                                    \
        for (int j = 0; j < 3; ++j) {                                        \
            const int r_ = wband + j * 8 + (lane >> 3);                      \
            const int cs_ = (lane & 7) ^ (r_ & 7);                           \
            gl_lds16(Wsrc + (size_t)r_ * NH + k0_ + cs_ * 4,                 \
                     wdst_ + (size_t)j * 8 * 32);                            \
        }                                                                    \
    } while (0)

    STAGE(0, 0);

    for (int kt = 0; kt < KT; ++kt) {
        const int cur = kt & 1;
        if (kt + 1 < KT) {
            STAGE(kt + 1, cur ^ 1);
            asm volatile("s_waitcnt vmcnt(7)" ::: "memory");  // tile kt landed
        } else {
            asm volatile("s_waitcnt vmcnt(0)" ::: "memory");
        }
        __builtin_amdgcn_s_barrier();

        short8 af[4], gf[3], uf[3];
        #pragma unroll
        for (int m = 0; m < 4; ++m) {
            const int R = wr * 64 + m * 16 + frow;
            const int p0 = (2 * h)     ^ (R & 7);
            const int p1 = (2 * h + 1) ^ (R & 7);
            af[m] = frag8(*(const floatx4*)&As[cur][R][p0 * 4],
                          *(const floatx4*)&As[cur][R][p1 * 4]);
        }
        #pragma unroll
        for (int n = 0; n < 3; ++n) {
            const int R = wc * 48 + n * 16 + frow;
            const int p0 = (2 * h)     ^ (R & 7);
            const int p1 = (2 * h + 1) ^ (R & 7);
            gf[n] = frag8(*(const floatx4*)&Gs[cur][R][p0 * 4],
                          *(const floatx4*)&Gs[cur][R][p1 * 4]);
            uf[n] = frag8(*(const floatx4*)&Us[cur][R][p0 * 4],
                          *(const floatx4*)&Us[cur][R][p1 * 4]);
        }
        #pragma unroll
        for (int m = 0; m < 4; ++m)
            #pragma unroll
            for (int n = 0; n < 3; ++n) {
                accg[m][n] = __builtin_amdgcn_mfma_f32_16x16x32_bf16(
                    af[m], gf[n], accg[m][n], 0, 0, 0);
                accu[m][n] = __builtin_amdgcn_mfma_f32_16x16x32_bf16(
                    af[m], uf[n], accu[m][n], 0, 0, 0);
            }

        asm volatile("s_waitcnt lgkmcnt(0)" ::: "memory");
        __builtin_amdgcn_sched_barrier(0);
        __builtin_amdgcn_s_barrier();
    }
#undef STAGE

    // Epilogue: silu(g)*u -> bf16. C/D: col=lane&15, row=(lane>>4)*4+reg.
    const int ccol  = lane & 15;
    const int crow0 = (lane >> 4) * 4;
    const size_t hbase = ((size_t)e * NT + (size_t)tm * 256) * NI + ti * 96;
    #pragma unroll
    for (int m = 0; m < 4; ++m)
        #pragma unroll
        for (int n = 0; n < 3; ++n)
            #pragma unroll
            for (int j = 0; j < 4; ++j) {
                const float g = accg[m][n][j];
                const float u = accu[m][n][j];
                const float hh = (g / (1.f + __expf(-g))) * u;
                const int row = wr * 64 + m * 16 + crow0 + j;
                const int col = wc * 48 + n * 16 + ccol;
                hidden[hbase + (size_t)row * NI + col] = f2bf(hh);
            }
}

// ---------------------------------------------------------------------------
// Kernel 2: down projection (unchanged, ~746 TF effective, L3-resident).
// ---------------------------------------------------------------------------
__global__ __launch_bounds__(256, 2) void moe_down(
    const ushort* __restrict__ hidden, const float* __restrict__ down,
    float* __restrict__ out)
{
    __shared__ ushort As[2][128][32];
    __shared__ float  Bs[2][128][32];

    const int bid = blockIdx.x;
    const int wg  = (bid & 7) * (2048 / 8) + (bid >> 3);
    const int e   = wg >> 6;
    const int rem = wg & 63;
    const int tn  = rem & 15;
    const int tm  = rem >> 4;

    const int tid  = threadIdx.x;
    const int lane = tid & 63;
    const int wave = tid >> 6;
    const int wr = wave >> 1, wc = wave & 1;

    const ushort* Ab = hidden + ((size_t)e * NT + (size_t)tm * 128) * NI;
    const float*  Bb = down + (size_t)e * NH * NI + (size_t)(tn * 128) * NI;

    floatx4 acc[4][4];
    #pragma unroll
    for (int m = 0; m < 4; ++m)
        #pragma unroll
        for (int n = 0; n < 4; ++n) acc[m][n] = (floatx4)0.f;

    const int frow = lane & 15;
    const int h    = lane >> 4;
    const int ca   = h ^ (frow & 3);
    const int rb   = frow & 7;
    const int c0   = (2 * h) ^ rb;
    const int c1   = (2 * h + 1) ^ rb;
    const int KT = NI / 32;

#define STAGE_DN(kt, b) do {                                                 \
        const int k0_ = (kt) * 32;                                           \
        _Pragma("unroll")                                                    \
        for (int i = 0; i < 2; ++i) {                                        \
            const int g_ = wave * 2 + i;                                     \
            const int r_ = g_ * 16 + (lane >> 2);                            \
            const int cs_ = (lane & 3) ^ (r_ & 3);                           \
            gl_lds16(Ab + (size_t)r_ * NI + k0_ + cs_ * 8, &As[b][g_ * 16][0]); \
        }                                                                    \
        _Pragma("unroll")                                                    \
        for (int i = 0; i < 4; ++i) {                                        \
            const int g_ = wave * 4 + i;                                     \
            const int r_ = g_ * 8 + (lane >> 3);                             \
            const int cs_ = (lane & 7) ^ (r_ & 7);                           \
            gl_lds16(Bb + (size_t)r_ * NI + k0_ + cs_ * 4, &Bs[b][g_ * 8][0]); \
        }                                                                    \
    } while (0)

    STAGE_DN(0, 0);

    for (int kt = 0; kt < KT; ++kt) {
        const int cur = kt & 1;
        if (kt + 1 < KT) {
            STAGE_DN(kt + 1, cur ^ 1);
            asm volatile("s_waitcnt vmcnt(6)" ::: "memory");
        } else {
            asm volatile("s_waitcnt vmcnt(0)" ::: "memory");
        }
        __builtin_amdgcn_s_barrier();

        short8 af[4], bf[4];
        #pragma unroll
        for (int m = 0; m < 4; ++m) {
            const int R = wr * 64 + m * 16 + frow;
            af[m] = *(const short8*)&As[cur][R][ca * 8];
        }
        #pragma unroll
        for (int n = 0; n < 4; ++n) {
            const int R = wc * 64 + n * 16 + frow;
            bf[n] = frag8(*(const floatx4*)&Bs[cur][R][c0 * 4],
                          *(const floatx4*)&Bs[cur][R][c1 * 4]);
        }
        #pragma unroll
        for (int m = 0; m < 4; ++m)
            #pragma unroll
            for (int n = 0; n < 4; ++n)
                acc[m][n] = __builtin_amdgcn_mfma_f32_16x16x32_bf16(
                    af[m], bf[n], acc[m][n], 0, 0, 0);

        asm volatile("s_waitcnt lgkmcnt(0)" ::: "memory");
        __builtin_amdgcn_sched_barrier(0);
        __builtin_amdgcn_s_barrier();
    }
#undef STAGE_DN

    const int ccol  = lane & 15;
    const int crow0 = (lane >> 4) * 4;
    float* Ob = out + ((size_t)e * NT + (size_t)tm * 128) * NH + tn * 128;
    #pragma unroll
    for (int m = 0; m < 4; ++m)
        #pragma unroll
        for (int n = 0; n < 4; ++n)
            #pragma unroll
            for (int j = 0; j < 4; ++j) {
                const int row = wr * 64 + m * 16 + crow0 + j;
                const int col = wc * 64 + n * 16 + ccol;
                Ob[(size_t)row * NH + col] = acc[m][n][j];
            }
}

extern "C" void kernel_launch(void* const* d_in, const int* in_sizes, int n_in,
                              void* d_out, int out_size, void* d_ws, size_t ws_size,
                              hipStream_t stream) {
    const float* rin  = (const float*)d_in[0];
    const float* gate = (const float*)d_in[1];
    const float* up   = (const float*)d_in[2];
    const float* down = (const float*)d_in[3];
    float* out = (float*)d_out;
    ushort* hidden = (ushort*)d_ws;   // [E,T,I] bf16, 24 MB

    moe_gateup<<<dim3(512), dim3(512), 0, stream>>>(rin, gate, up, hidden);
    moe_down<<<dim3(2048), dim3(256), 0, stream>>>(hidden, down, out);
}

// Round 11
// 356.382 us; speedup vs baseline: 1.5828x; 1.0468x over previous
//
#include <hip/hip_runtime.h>

// Qwen3 MoE experts: per-expert SwiGLU MLP.
//   gate = rin @ gate_proj^T ; up = rin @ up_proj^T
//   hidden = silu(gate) * up ; out = hidden @ down_proj^T
// E=32, T=512, H=2048, I=768. f32 inputs; bf16 MFMA, f32 accum.
//
// R10: depth-2 prefetch at full tile. Model: depth-1 dbuf pays one
//      barrier-coupled HBM-miss tail (~2000 cyc) EVERY iteration (536 MB
//      footprint > L3) -> ~290us invariant of tile/volume (R2..R9).
//      Fix: triple-buffered LDS, STAGE(k+2) issued 2 iters ahead,
//      vmcnt(12) counted wait, 512 thr = 8 waves = 2/SIMD (1 block/CU).
// ws: hidden [E,T,I] bf16 = 24 MB.

#define NE 32
#define NT 512
#define NH 2048
#define NI 768

typedef short        short8  __attribute__((ext_vector_type(8)));
typedef float        floatx4 __attribute__((ext_vector_type(4)));
typedef __attribute__((address_space(1))) const unsigned int g_u32;
typedef __attribute__((address_space(3))) unsigned int l_u32;

__device__ __forceinline__ void gl_lds16(const void* g, void* l) {
    __builtin_amdgcn_global_load_lds((g_u32*)g, (l_u32*)l, 16, 0, 0);
}

__device__ __forceinline__ unsigned int cvt_pk_bf16(float lo, float hi) {
    unsigned int r;
    asm("v_cvt_pk_bf16_f32 %0, %1, %2" : "=v"(r) : "v"(lo), "v"(hi));
    return r;
}

__device__ __forceinline__ short8 frag8(floatx4 x0, floatx4 x1) {
    union { unsigned int u[4]; short8 s; } t;
    t.u[0] = cvt_pk_bf16(x0[0], x0[1]);
    t.u[1] = cvt_pk_bf16(x0[2], x0[3]);
    t.u[2] = cvt_pk_bf16(x1[0], x1[1]);
    t.u[3] = cvt_pk_bf16(x1[2], x1[3]);
    return t.s;
}

__device__ __forceinline__ ushort f2bf(float f) {
    union { float f; unsigned int u; } v; v.f = f;
    unsigned int r = v.u + 0x7fffu + ((v.u >> 16) & 1u);
    return (ushort)(r >> 16);
}

// ---------------------------------------------------------------------------
// Kernel 1: fused gate+up + SwiGLU -> hidden(bf16).
// BM=128(T) x BN=128(I), BK=32 over H. 512 thr = 8 waves as 4(T-band 32) x
// 2(I-band 64); per GEMM 2x4 frags of 16x16 -> acc 64 AGPR total.
// LDS: S[3 bufs][3 tiles][128][32] f32 = 144 KB. Prefetch distance 2.
// Staging: 48 gl_lds(16B)/stage, 6 per wave; source chunk-XOR swizzle.
// ---------------------------------------------------------------------------
__global__ __launch_bounds__(512, 1) void moe_gateup(
    const float* __restrict__ rin, const float* __restrict__ gate,
    const float* __restrict__ up, ushort* __restrict__ hidden)
{
    __shared__ float S[3][3][128][32];   // [buf][A,G,U][row][col]

    // XCD-bijective swizzle: 768 blocks, chunk 96
    const int bid = blockIdx.x;
    const int wg  = (bid & 7) * 96 + (bid >> 3);
    const int e   = wg / 24;
    const int rem = wg % 24;
    const int ti  = rem % 6;    // I tile of 128
    const int tm  = rem / 6;    // T tile of 128

    const int tid  = threadIdx.x;
    const int lane = tid & 63;
    const int wave = tid >> 6;          // 0..7
    const int wr = wave >> 1;           // 0..3: T band of 32
    const int wc = wave & 1;            // 0..1: I band of 64

    const float* Ab = rin  + (size_t)e * NT * NH + (size_t)(tm * 128) * NH;
    const float* Gb = gate + (size_t)e * NI * NH + (size_t)(ti * 128) * NH;
    const float* Ub = up   + (size_t)e * NI * NH + (size_t)(ti * 128) * NH;

    floatx4 accg[2][4], accu[2][4];
    #pragma unroll
    for (int m = 0; m < 2; ++m)
        #pragma unroll
        for (int n = 0; n < 4; ++n) {
            accg[m][n] = (floatx4)0.f;
            accu[m][n] = (floatx4)0.f;
        }

    const int frow = lane & 15;
    const int h    = lane >> 4;
    const int KT = NH / 32;   // 64

    // 48 insts/stage, 6 per wave. Linear list: idx 0-15 A, 16-31 G, 32-47 U;
    // inst covers rows [ri*8, ri*8+8) of its tile (1 KB).
#define STAGE(kt, b) do {                                                    \
        const int k0_ = (kt) * 32;                                           \
        _Pragma("unroll")                                                    \
        for (int i = 0; i < 6; ++i) {                                        \
            const int idx = wave * 6 + i;                                    \
            const int t_  = idx >> 4;                                        \
            const int ri  = idx & 15;                                        \
            const int r_  = ri * 8 + (lane >> 3);                            \
            const int cs_ = (lane & 7) ^ (r_ & 7);                           \
            const float* src = (t_ == 0 ? Ab : (t_ == 1 ? Gb : Ub))          \
                               + (size_t)r_ * NH + k0_ + cs_ * 4;            \
            gl_lds16(src, &S[b][t_][ri * 8][0]);                             \
        }                                                                    \
    } while (0)

    // prologue: tiles 0,1 in flight
    STAGE(0, 0);
    STAGE(1, 1);

    for (int kt = 0; kt < KT; ++kt) {
        const int cur = kt % 3;
        __builtin_amdgcn_s_barrier();   // buf (kt+2)%3 free (compute kt-1 done)
        if (kt + 2 < KT) {
            STAGE(kt + 2, (kt + 2) % 3);
            asm volatile("s_waitcnt vmcnt(12)" ::: "memory"); // tile kt landed
        } else if (kt + 1 < KT) {
            asm volatile("s_waitcnt vmcnt(6)" ::: "memory");
        } else {
            asm volatile("s_waitcnt vmcnt(0)" ::: "memory");
        }
        __builtin_amdgcn_s_barrier();   // tile kt landed for ALL waves

        short8 af[2], gf[4], uf[4];
        #pragma unroll
        for (int m = 0; m < 2; ++m) {
            const int R = wr * 32 + m * 16 + frow;
            const int p0 = (2 * h)     ^ (R & 7);
            const int p1 = (2 * h + 1) ^ (R & 7);
            af[m] = frag8(*(const floatx4*)&S[cur][0][R][p0 * 4],
                          *(const floatx4*)&S[cur][0][R][p1 * 4]);
        }
        #pragma unroll
        for (int n = 0; n < 4; ++n) {
            const int R = wc * 64 + n * 16 + frow;
            const int p0 = (2 * h)     ^ (R & 7);
            const int p1 = (2 * h + 1) ^ (R & 7);
            gf[n] = frag8(*(const floatx4*)&S[cur][1][R][p0 * 4],
                          *(const floatx4*)&S[cur][1][R][p1 * 4]);
            uf[n] = frag8(*(const floatx4*)&S[cur][2][R][p0 * 4],
                          *(const floatx4*)&S[cur][2][R][p1 * 4]);
        }
        #pragma unroll
        for (int m = 0; m < 2; ++m)
            #pragma unroll
            for (int n = 0; n < 4; ++n) {
                accg[m][n] = __builtin_amdgcn_mfma_f32_16x16x32_bf16(
                    af[m], gf[n], accg[m][n], 0, 0, 0);
                accu[m][n] = __builtin_amdgcn_mfma_f32_16x16x32_bf16(
                    af[m], uf[n], accu[m][n], 0, 0, 0);
            }

        asm volatile("s_waitcnt lgkmcnt(0)" ::: "memory");
        __builtin_amdgcn_sched_barrier(0);
    }
#undef STAGE

    // Epilogue: silu(g)*u -> bf16. C/D: col=lane&15, row=(lane>>4)*4+reg.
    const int ccol  = lane & 15;
    const int crow0 = (lane >> 4) * 4;
    const size_t hbase = ((size_t)e * NT + (size_t)tm * 128) * NI + ti * 128;
    #pragma unroll
    for (int m = 0; m < 2; ++m)
        #pragma unroll
        for (int n = 0; n < 4; ++n)
            #pragma unroll
            for (int j = 0; j < 4; ++j) {
                const float g = accg[m][n][j];
                const float u = accu[m][n][j];
                const float hh = (g / (1.f + __expf(-g))) * u;
                const int row = wr * 32 + m * 16 + crow0 + j;
                const int col = wc * 64 + n * 16 + ccol;
                hidden[hbase + (size_t)row * NI + col] = f2bf(hh);
            }
}

// ---------------------------------------------------------------------------
// Kernel 2: down projection (unchanged, ~746 TF effective, L3-resident).
// ---------------------------------------------------------------------------
__global__ __launch_bounds__(256, 2) void moe_down(
    const ushort* __restrict__ hidden, const float* __restrict__ down,
    float* __restrict__ out)
{
    __shared__ ushort As[2][128][32];
    __shared__ float  Bs[2][128][32];

    const int bid = blockIdx.x;
    const int wg  = (bid & 7) * (2048 / 8) + (bid >> 3);
    const int e   = wg >> 6;
    const int rem = wg & 63;
    const int tn  = rem & 15;
    const int tm  = rem >> 4;

    const int tid  = threadIdx.x;
    const int lane = tid & 63;
    const int wave = tid >> 6;
    const int wr = wave >> 1, wc = wave & 1;

    const ushort* Ab = hidden + ((size_t)e * NT + (size_t)tm * 128) * NI;
    const float*  Bb = down + (size_t)e * NH * NI + (size_t)(tn * 128) * NI;

    floatx4 acc[4][4];
    #pragma unroll
    for (int m = 0; m < 4; ++m)
        #pragma unroll
        for (int n = 0; n < 4; ++n) acc[m][n] = (floatx4)0.f;

    const int frow = lane & 15;
    const int h    = lane >> 4;
    const int ca   = h ^ (frow & 3);
    const int rb   = frow & 7;
    const int c0   = (2 * h) ^ rb;
    const int c1   = (2 * h + 1) ^ rb;
    const int KT = NI / 32;

#define STAGE_DN(kt, b) do {                                                 \
        const int k0_ = (kt) * 32;                                           \
        _Pragma("unroll")                                                    \
        for (int i = 0; i < 2; ++i) {                                        \
            const int g_ = wave * 2 + i;                                     \
            const int r_ = g_ * 16 + (lane >> 2);                            \
            const int cs_ = (lane & 3) ^ (r_ & 3);                           \
            gl_lds16(Ab + (size_t)r_ * NI + k0_ + cs_ * 8, &As[b][g_ * 16][0]); \
        }                                                                    \
        _Pragma("unroll")                                                    \
        for (int i = 0; i < 4; ++i) {                                        \
            const int g_ = wave * 4 + i;                                     \
            const int r_ = g_ * 8 + (lane >> 3);                             \
            const int cs_ = (lane & 7) ^ (r_ & 7);                           \
            gl_lds16(Bb + (size_t)r_ * NI + k0_ + cs_ * 4, &Bs[b][g_ * 8][0]); \
        }                                                                    \
    } while (0)

    STAGE_DN(0, 0);

    for (int kt = 0; kt < KT; ++kt) {
        const int cur = kt & 1;
        if (kt + 1 < KT) {
            STAGE_DN(kt + 1, cur ^ 1);
            asm volatile("s_waitcnt vmcnt(6)" ::: "memory");
        } else {
            asm volatile("s_waitcnt vmcnt(0)" ::: "memory");
        }
        __builtin_amdgcn_s_barrier();

        short8 af[4], bf[4];
        #pragma unroll
        for (int m = 0; m < 4; ++m) {
            const int R = wr * 64 + m * 16 + frow;
            af[m] = *(const short8*)&As[cur][R][ca * 8];
        }
        #pragma unroll
        for (int n = 0; n < 4; ++n) {
            const int R = wc * 64 + n * 16 + frow;
            bf[n] = frag8(*(const floatx4*)&Bs[cur][R][c0 * 4],
                          *(const floatx4*)&Bs[cur][R][c1 * 4]);
        }
        #pragma unroll
        for (int m = 0; m < 4; ++m)
            #pragma unroll
            for (int n = 0; n < 4; ++n)
                acc[m][n] = __builtin_amdgcn_mfma_f32_16x16x32_bf16(
                    af[m], bf[n], acc[m][n], 0, 0, 0);

        asm volatile("s_waitcnt lgkmcnt(0)" ::: "memory");
        __builtin_amdgcn_sched_barrier(0);
        __builtin_amdgcn_s_barrier();
    }
#undef STAGE_DN

    const int ccol  = lane & 15;
    const int crow0 = (lane >> 4) * 4;
    float* Ob = out + ((size_t)e * NT + (size_t)tm * 128) * NH + tn * 128;
    #pragma unroll
    for (int m = 0; m < 4; ++m)
        #pragma unroll
        for (int n = 0; n < 4; ++n)
            #pragma unroll
            for (int j = 0; j < 4; ++j) {
                const int row = wr * 64 + m * 16 + crow0 + j;
                const int col = wc * 64 + n * 16 + ccol;
                Ob[(size_t)row * NH + col] = acc[m][n][j];
            }
}

extern "C" void kernel_launch(void* const* d_in, const int* in_sizes, int n_in,
                              void* d_out, int out_size, void* d_ws, size_t ws_size,
                              hipStream_t stream) {
    const float* rin  = (const float*)d_in[0];
    const float* gate = (const float*)d_in[1];
    const float* up   = (const float*)d_in[2];
    const float* down = (const float*)d_in[3];
    float* out = (float*)d_out;
    ushort* hidden = (ushort*)d_ws;   // [E,T,I] bf16, 24 MB

    moe_gateup<<<dim3(768), dim3(512), 0, stream>>>(rin, gate, up, hidden);
    moe_down<<<dim3(2048), dim3(256), 0, stream>>>(hidden, down, out);
}

// Round 12
// 349.587 us; speedup vs baseline: 1.6136x; 1.0194x over previous
//
#include <hip/hip_runtime.h>

// Qwen3 MoE experts: per-expert SwiGLU MLP.
//   gate = rin @ gate_proj^T ; up = rin @ up_proj^T
//   hidden = silu(gate) * up ; out = hidden @ down_proj^T
// E=32, T=512, H=2048, I=768. f32 inputs; bf16 MFMA, f32 accum.
//
// R11: LDS-bandwidth model. down is AT the ds_read_b128 ceiling (83 B/cyc);
//      gateup's f32-staged tiles + 4x2 grid moved 208 KB/CU-iter of LDS
//      traffic (~1900 cyc) -> the invariant ~290us. Fix: bf16-in-LDS
//      (halves bytes), 2x4 wave grid (A x4, G/U x2 amp -> 88 KB/CU-iter),
//      reg-staging with PRE-SWIZZLED global source + LINEAR ds_write_b128
//      (zero write conflicts), read chunk XOR h^(R&3) (down's proven
//      pattern), depth-2 reg prefetch with per-register compiler waits
//      (no vmcnt asm), raw s_barrier so prefetch crosses barriers.
// ws: hidden [E,T,I] bf16 = 24 MB.

#define NE 32
#define NT 512
#define NH 2048
#define NI 768

typedef short        short8  __attribute__((ext_vector_type(8)));
typedef float        floatx4 __attribute__((ext_vector_type(4)));
typedef unsigned int uintx4  __attribute__((ext_vector_type(4)));
typedef __attribute__((address_space(1))) const unsigned int g_u32;
typedef __attribute__((address_space(3))) unsigned int l_u32;

__device__ __forceinline__ void gl_lds16(const void* g, void* l) {
    __builtin_amdgcn_global_load_lds((g_u32*)g, (l_u32*)l, 16, 0, 0);
}

__device__ __forceinline__ unsigned int cvt_pk_bf16(float lo, float hi) {
    unsigned int r;
    asm("v_cvt_pk_bf16_f32 %0, %1, %2" : "=v"(r) : "v"(lo), "v"(hi));
    return r;
}

__device__ __forceinline__ short8 frag8(floatx4 x0, floatx4 x1) {
    union { unsigned int u[4]; short8 s; } t;
    t.u[0] = cvt_pk_bf16(x0[0], x0[1]);
    t.u[1] = cvt_pk_bf16(x0[2], x0[3]);
    t.u[2] = cvt_pk_bf16(x1[0], x1[1]);
    t.u[3] = cvt_pk_bf16(x1[2], x1[3]);
    return t.s;
}

__device__ __forceinline__ uintx4 pack8(floatx4 x0, floatx4 x1) {
    uintx4 u;
    u[0] = cvt_pk_bf16(x0[0], x0[1]);
    u[1] = cvt_pk_bf16(x0[2], x0[3]);
    u[2] = cvt_pk_bf16(x1[0], x1[1]);
    u[3] = cvt_pk_bf16(x1[2], x1[3]);
    return u;
}

__device__ __forceinline__ ushort f2bf(float f) {
    union { float f; unsigned int u; } v; v.f = f;
    unsigned int r = v.u + 0x7fffu + ((v.u >> 16) & 1u);
    return (ushort)(r >> 16);
}

// ---------------------------------------------------------------------------
// Kernel 1: fused gate+up + SwiGLU -> hidden(bf16).
// BM=128(T) x BN=128(I), BK=32 over H. 512 thr = 8 waves as WM=2 (T band 64)
// x WN=4 (I band 32). Per GEMM: 4x2 frags of 16x16; acc = 64 AGPR.
// LDS: bf16 S[2][3][128][32] = 48 KB. Staging: per wave 16-row band of each
// tile; lane l -> row wave*16+(l>>2), phys chunk l&3 (LINEAR write), global
// source logical chunk c = (l&3)^(row&3) (pre-swizzle). Reads: p = h^(R&3).
// Depth-2 reg prefetch: loads(kt+2) issued at kt, ds_write at kt+1.
// ---------------------------------------------------------------------------
__global__ __launch_bounds__(512, 1) void moe_gateup(
    const float* __restrict__ rin, const float* __restrict__ gate,
    const float* __restrict__ up, ushort* __restrict__ hidden)
{
    __shared__ ushort S[2][3][128][32];   // [buf][A,G,U][row][k]

    // XCD-bijective swizzle: 768 blocks, chunk 96
    const int bid = blockIdx.x;
    const int wg  = (bid & 7) * 96 + (bid >> 3);
    const int e   = wg / 24;
    const int rem = wg % 24;
    const int ti  = rem % 6;    // I tile of 128
    const int tm  = rem / 6;    // T tile of 128

    const int tid  = threadIdx.x;
    const int lane = tid & 63;
    const int wave = tid >> 6;          // 0..7
    const int wr = wave >> 2;           // 0..1: T band of 64
    const int wc = wave & 3;            // 0..3: I band of 32

    const float* Ab = rin  + (size_t)e * NT * NH + (size_t)(tm * 128) * NH;
    const float* Gb = gate + (size_t)e * NI * NH + (size_t)(ti * 128) * NH;
    const float* Ub = up   + (size_t)e * NI * NH + (size_t)(ti * 128) * NH;

    // staging geometry
    const int s_row = wave * 16 + (lane >> 2);      // row in [wave*16, +16)
    const int s_cl  = lane & 3;                     // phys chunk (linear)
    const int s_c   = s_cl ^ (s_row & 3);           // logical chunk (source)
    const float* As_src = Ab + (size_t)s_row * NH + s_c * 8;
    const float* Gs_src = Gb + (size_t)s_row * NH + s_c * 8;
    const float* Us_src = Ub + (size_t)s_row * NH + s_c * 8;

    floatx4 accg[4][2], accu[4][2];
    #pragma unroll
    for (int m = 0; m < 4; ++m)
        #pragma unroll
        for (int n = 0; n < 2; ++n) {
            accg[m][n] = (floatx4)0.f;
            accu[m][n] = (floatx4)0.f;
        }

    const int frow = lane & 15;
    const int h    = lane >> 4;          // k chunk 0..3
    const int KT = NH / 32;              // 64

    // prefetch registers: two parities, 3 tiles x 2 floatx4 each
    floatx4 pA0[3][2], pA1[3][2];

#define ISSUE(kt, P) do {                                                    \
        const int k_ = (kt) * 32;                                            \
        P[0][0] = *(const floatx4*)(As_src + k_);                            \
        P[0][1] = *(const floatx4*)(As_src + k_ + 4);                        \
        P[1][0] = *(const floatx4*)(Gs_src + k_);                            \
        P[1][1] = *(const floatx4*)(Gs_src + k_ + 4);                        \
        P[2][0] = *(const floatx4*)(Us_src + k_);                            \
        P[2][1] = *(const floatx4*)(Us_src + k_ + 4);                        \
    } while (0)

#define WRITE(b, P) do {                                                     \
        *(uintx4*)&S[b][0][s_row][s_cl * 8] = pack8(P[0][0], P[0][1]);       \
        *(uintx4*)&S[b][1][s_row][s_cl * 8] = pack8(P[1][0], P[1][1]);       \
        *(uintx4*)&S[b][2][s_row][s_cl * 8] = pack8(P[2][0], P[2][1]);       \
    } while (0)

#define COMPUTE(b) do {                                                      \
        short8 af[4], gf[2], uf[2];                                          \
        _Pragma("unroll")                                                    \
        for (int m = 0; m < 4; ++m) {                                        \
            const int R = wr * 64 + m * 16 + frow;                           \
            const int p = h ^ (R & 3);                                       \
            af[m] = *(const short8*)&S[b][0][R][p * 8];                      \
        }                                                                    \
        _Pragma("unroll")                                                    \
        for (int n = 0; n < 2; ++n) {                                        \
            const int R = wc * 32 + n * 16 + frow;                           \
            const int p = h ^ (R & 3);                                       \
            gf[n] = *(const short8*)&S[b][1][R][p * 8];                      \
            uf[n] = *(const short8*)&S[b][2][R][p * 8];                      \
        }                                                                    \
        _Pragma("unroll")                                                    \
        for (int m = 0; m < 4; ++m)                                          \
            _Pragma("unroll")                                                \
            for (int n = 0; n < 2; ++n) {                                    \
                accg[m][n] = __builtin_amdgcn_mfma_f32_16x16x32_bf16(        \
                    af[m], gf[n], accg[m][n], 0, 0, 0);                      \
                accu[m][n] = __builtin_amdgcn_mfma_f32_16x16x32_bf16(        \
                    af[m], uf[n], accu[m][n], 0, 0, 0);                      \
            }                                                                \
    } while (0)

#define ENDBAR() do {                                                        \
        asm volatile("s_waitcnt lgkmcnt(0)" ::: "memory");                   \
        __builtin_amdgcn_sched_barrier(0);                                   \
        __builtin_amdgcn_s_barrier();                                        \
    } while (0)

    // prologue: tile 0 -> regs P0 -> LDS buf0; tile 1 -> regs P1 (in flight)
    ISSUE(0, pA0);
    ISSUE(1, pA1);
    WRITE(0, pA0);
    ENDBAR();

    // steady state, unrolled by 2 for static reg-parity indexing (rule #20)
    for (int kt = 0; kt < KT; kt += 2) {
        // iter kt (cur buf 0): write tile kt+1 (regs P1) -> buf1,
        // issue tile kt+2 -> regs P0, compute buf0.
        if (kt + 2 < KT) ISSUE(kt + 2, pA0);
        WRITE(1, pA1);
        COMPUTE(0);
        ENDBAR();
        // iter kt+1 (cur buf 1): write tile kt+2 (regs P0) -> buf0,
        // issue tile kt+3 -> regs P1, compute buf1.
        if (kt + 3 < KT) ISSUE(kt + 3, pA1);
        if (kt + 2 < KT) WRITE(0, pA0);
        COMPUTE(1);
        ENDBAR();
    }
#undef ISSUE
#undef WRITE
#undef COMPUTE
#undef ENDBAR

    // Epilogue: silu(g)*u -> bf16. C/D: col=lane&15, row=(lane>>4)*4+reg.
    const int ccol  = lane & 15;
    const int crow0 = (lane >> 4) * 4;
    const size_t hbase = ((size_t)e * NT + (size_t)tm * 128) * NI + ti * 128;
    #pragma unroll
    for (int m = 0; m < 4; ++m)
        #pragma unroll
        for (int n = 0; n < 2; ++n)
            #pragma unroll
            for (int j = 0; j < 4; ++j) {
                const float g = accg[m][n][j];
                const float u = accu[m][n][j];
                const float hh = (g / (1.f + __expf(-g))) * u;
                const int row = wr * 64 + m * 16 + crow0 + j;
                const int col = wc * 32 + n * 16 + ccol;
                hidden[hbase + (size_t)row * NI + col] = f2bf(hh);
            }
}

// ---------------------------------------------------------------------------
// Kernel 2: down projection (unchanged — at the LDS throughput ceiling).
// ---------------------------------------------------------------------------
__global__ __launch_bounds__(256, 2) void moe_down(
    const ushort* __restrict__ hidden, const float* __restrict__ down,
    float* __restrict__ out)
{
    __shared__ ushort As[2][128][32];
    __shared__ float  Bs[2][128][32];

    const int bid = blockIdx.x;
    const int wg  = (bid & 7) * (2048 / 8) + (bid >> 3);
    const int e   = wg >> 6;
    const int rem = wg & 63;
    const int tn  = rem & 15;
    const int tm  = rem >> 4;

    const int tid  = threadIdx.x;
    const int lane = tid & 63;
    const int wave = tid >> 6;
    const int wr = wave >> 1, wc = wave & 1;

    const ushort* Ab = hidden + ((size_t)e * NT + (size_t)tm * 128) * NI;
    const float*  Bb = down + (size_t)e * NH * NI + (size_t)(tn * 128) * NI;

    floatx4 acc[4][4];
    #pragma unroll
    for (int m = 0; m < 4; ++m)
        #pragma unroll
        for (int n = 0; n < 4; ++n) acc[m][n] = (floatx4)0.f;

    const int frow = lane & 15;
    const int h    = lane >> 4;
    const int ca   = h ^ (frow & 3);
    const int rb   = frow & 7;
    const int c0   = (2 * h) ^ rb;
    const int c1   = (2 * h + 1) ^ rb;
    const int KT = NI / 32;

#define STAGE_DN(kt, b) do {                                                 \
        const int k0_ = (kt) * 32;                                           \
        _Pragma("unroll")                                                    \
        for (int i = 0; i < 2; ++i) {                                        \
            const int g_ = wave * 2 + i;                                     \
            const int r_ = g_ * 16 + (lane >> 2);                            \
            const int cs_ = (lane & 3) ^ (r_ & 3);                           \
            gl_lds16(Ab + (size_t)r_ * NI + k0_ + cs_ * 8, &As[b][g_ * 16][0]); \
        }                                                                    \
        _Pragma("unroll")                                                    \
        for (int i = 0; i < 4; ++i) {                                        \
            const int g_ = wave * 4 + i;                                     \
            const int r_ = g_ * 8 + (lane >> 3);                             \
            const int cs_ = (lane & 7) ^ (r_ & 7);                           \
            gl_lds16(Bb + (size_t)r_ * NI + k0_ + cs_ * 4, &Bs[b][g_ * 8][0]); \
        }                                                                    \
    } while (0)

    STAGE_DN(0, 0);

    for (int kt = 0; kt < KT; ++kt) {
        const int cur = kt & 1;
        if (kt + 1 < KT) {
            STAGE_DN(kt + 1, cur ^ 1);
            asm volatile("s_waitcnt vmcnt(6)" ::: "memory");
        } else {
            asm volatile("s_waitcnt vmcnt(0)" ::: "memory");
        }
        __builtin_amdgcn_s_barrier();

        short8 af[4], bf[4];
        #pragma unroll
        for (int m = 0; m < 4; ++m) {
            const int R = wr * 64 + m * 16 + frow;
            af[m] = *(const short8*)&As[cur][R][ca * 8];
        }
        #pragma unroll
        for (int n = 0; n < 4; ++n) {
            const int R = wc * 64 + n * 16 + frow;
            bf[n] = frag8(*(const floatx4*)&Bs[cur][R][c0 * 4],
                          *(const floatx4*)&Bs[cur][R][c1 * 4]);
        }
        #pragma unroll
        for (int m = 0; m < 4; ++m)
            #pragma unroll
            for (int n = 0; n < 4; ++n)
                acc[m][n] = __builtin_amdgcn_mfma_f32_16x16x32_bf16(
                    af[m], bf[n], acc[m][n], 0, 0, 0);

        asm volatile("s_waitcnt lgkmcnt(0)" ::: "memory");
        __builtin_amdgcn_sched_barrier(0);
        __builtin_amdgcn_s_barrier();
    }
#undef STAGE_DN

    const int ccol  = lane & 15;
    const int crow0 = (lane >> 4) * 4;
    float* Ob = out + ((size_t)e * NT + (size_t)tm * 128) * NH + tn * 128;
    #pragma unroll
    for (int m = 0; m < 4; ++m)
        #pragma unroll
        for (int n = 0; n < 4; ++n)
            #pragma unroll
            for (int j = 0; j < 4; ++j) {
                const int row = wr * 64 + m * 16 + crow0 + j;
                const int col = wc * 64 + n * 16 + ccol;
                Ob[(size_t)row * NH + col] = acc[m][n][j];
            }
}

extern "C" void kernel_launch(void* const* d_in, const int* in_sizes, int n_in,
                              void* d_out, int out_size, void* d_ws, size_t ws_size,
                              hipStream_t stream) {
    const float* rin  = (const float*)d_in[0];
    const float* gate = (const float*)d_in[1];
    const float* up   = (const float*)d_in[2];
    const float* down = (const float*)d_in[3];
    float* out = (float*)d_out;
    ushort* hidden = (ushort*)d_ws;   // [E,T,I] bf16, 24 MB

    moe_gateup<<<dim3(768), dim3(512), 0, stream>>>(rin, gate, up, hidden);
    moe_down<<<dim3(2048), dim3(256), 0, stream>>>(hidden, down, out);
}

// Round 13
// 336.544 us; speedup vs baseline: 1.6761x; 1.0388x over previous
//
#include <hip/hip_runtime.h>

// Qwen3 MoE experts: per-expert SwiGLU MLP.
//   gate = rin @ gate_proj^T ; up = rin @ up_proj^T
//   hidden = silu(gate) * up ; out = hidden @ down_proj^T
// E=32, T=512, H=2048, I=768. f32 inputs; bf16 MFMA, f32 accum.
//
// R13: independent-streams model. 12-round invariant (~270-300us gateup)
//      tracks resident independent blocks/CU, not tile/volume/LDS: every
//      variant had 1-2 lockstepped streams; down (2+ interleaved blocks)
//      runs 4x faster per staged byte. Fix: 256-thr blocks, BM=128 BN=64,
//      LDS 32 KB, 64 AGPR acc, launch_bounds(256,3) -> 3 blocks/CU.
//      Reg-staged bf16 dbuf, T14 order (COMPUTE -> WRITE -> ISSUE),
//      compiler-tracked waits, raw s_barrier.
// ws: hidden [E,T,I] bf16 = 24 MB.

#define NE 32
#define NT 512
#define NH 2048
#define NI 768

typedef short        short8  __attribute__((ext_vector_type(8)));
typedef float        floatx4 __attribute__((ext_vector_type(4)));
typedef unsigned int uintx4  __attribute__((ext_vector_type(4)));
typedef __attribute__((address_space(1))) const unsigned int g_u32;
typedef __attribute__((address_space(3))) unsigned int l_u32;

__device__ __forceinline__ void gl_lds16(const void* g, void* l) {
    __builtin_amdgcn_global_load_lds((g_u32*)g, (l_u32*)l, 16, 0, 0);
}

__device__ __forceinline__ unsigned int cvt_pk_bf16(float lo, float hi) {
    unsigned int r;
    asm("v_cvt_pk_bf16_f32 %0, %1, %2" : "=v"(r) : "v"(lo), "v"(hi));
    return r;
}

__device__ __forceinline__ short8 frag8(floatx4 x0, floatx4 x1) {
    union { unsigned int u[4]; short8 s; } t;
    t.u[0] = cvt_pk_bf16(x0[0], x0[1]);
    t.u[1] = cvt_pk_bf16(x0[2], x0[3]);
    t.u[2] = cvt_pk_bf16(x1[0], x1[1]);
    t.u[3] = cvt_pk_bf16(x1[2], x1[3]);
    return t.s;
}

__device__ __forceinline__ uintx4 pack8(floatx4 x0, floatx4 x1) {
    uintx4 u;
    u[0] = cvt_pk_bf16(x0[0], x0[1]);
    u[1] = cvt_pk_bf16(x0[2], x0[3]);
    u[2] = cvt_pk_bf16(x1[0], x1[1]);
    u[3] = cvt_pk_bf16(x1[2], x1[3]);
    return u;
}

__device__ __forceinline__ ushort f2bf(float f) {
    union { float f; unsigned int u; } v; v.f = f;
    unsigned int r = v.u + 0x7fffu + ((v.u >> 16) & 1u);
    return (ushort)(r >> 16);
}

// ---------------------------------------------------------------------------
// Kernel 1: fused gate+up + SwiGLU -> hidden(bf16).
// BM=128(T) x BN=64(I), BK=32 over H. 256 thr = 4 waves as 2(T band 64) x
// 2(I band 32). Per GEMM 4x2 frags of 16x16 -> acc = 64 AGPR.
// LDS: bf16 SA[2][128][32] + SG,SU[2][64][32] = 32 KB -> 3 blocks/CU.
// Staging: reg path, pre-swizzled source chunk c = phys ^ (row&3), LINEAR
// phys write, read at p = h ^ (R&3) (R12's proven pattern).
// ---------------------------------------------------------------------------
__global__ __launch_bounds__(256, 3) void moe_gateup(
    const float* __restrict__ rin, const float* __restrict__ gate,
    const float* __restrict__ up, ushort* __restrict__ hidden)
{
    __shared__ ushort SA[2][128][32];
    __shared__ ushort SG[2][64][32];
    __shared__ ushort SU[2][64][32];

    // XCD-bijective swizzle: 1536 blocks, chunk 192
    const int bid = blockIdx.x;
    const int wg  = (bid & 7) * 192 + (bid >> 3);
    const int e   = wg / 48;
    const int rem = wg % 48;
    const int ti  = rem % 12;   // I tile of 64
    const int tm  = rem / 12;   // T tile of 128

    const int tid  = threadIdx.x;
    const int lane = tid & 63;
    const int wave = tid >> 6;          // 0..3
    const int wr = wave >> 1;           // 0..1: T band of 64
    const int wc = wave & 1;            // 0..1: I band of 32

    const float* Ab = rin  + (size_t)e * NT * NH + (size_t)(tm * 128) * NH;
    const float* Gb = gate + (size_t)e * NI * NH + (size_t)(ti * 64) * NH;
    const float* Ub = up   + (size_t)e * NI * NH + (size_t)(ti * 64) * NH;

    // staging geometry (phys chunk LINEAR, source pre-swizzled)
    // A: slots tid and tid+256 -> row s>>2, phys s&3
    const int a0_row = tid >> 2,            a0_cl = tid & 3;
    const int a1_row = (tid + 256) >> 2,    a1_cl = tid & 3;
    const int a0_c = a0_cl ^ (a0_row & 3);
    const int a1_c = a1_cl ^ (a1_row & 3);
    // G/U: row tid>>2 (0..63), phys tid&3
    const int w_row = tid >> 2,             w_cl = tid & 3;
    const int w_c = w_cl ^ (w_row & 3);

    const float* A0src = Ab + (size_t)a0_row * NH + a0_c * 8;
    const float* A1src = Ab + (size_t)a1_row * NH + a1_c * 8;
    const float* Gsrc  = Gb + (size_t)w_row * NH + w_c * 8;
    const float* Usrc  = Ub + (size_t)w_row * NH + w_c * 8;

    floatx4 accg[4][2], accu[4][2];
    #pragma unroll
    for (int m = 0; m < 4; ++m)
        #pragma unroll
        for (int n = 0; n < 2; ++n) {
            accg[m][n] = (floatx4)0.f;
            accu[m][n] = (floatx4)0.f;
        }

    const int frow = lane & 15;
    const int h    = lane >> 4;          // logical k-chunk 0..3
    const int KT = NH / 32;              // 64

    floatx4 P[4][2];   // [A0,A1,G,U][half] prefetch regs (32 VGPR)

#define ISSUE(kt) do {                                                       \
        const int k_ = (kt) * 32;                                            \
        P[0][0] = *(const floatx4*)(A0src + k_);                             \
        P[0][1] = *(const floatx4*)(A0src + k_ + 4);                         \
        P[1][0] = *(const floatx4*)(A1src + k_);                             \
        P[1][1] = *(const floatx4*)(A1src + k_ + 4);                         \
        P[2][0] = *(const floatx4*)(Gsrc + k_);                              \
        P[2][1] = *(const floatx4*)(Gsrc + k_ + 4);                          \
        P[3][0] = *(const floatx4*)(Usrc + k_);                              \
        P[3][1] = *(const floatx4*)(Usrc + k_ + 4);                          \
    } while (0)

#define WRITE(b) do {                                                       \
        *(uintx4*)&SA[b][a0_row][a0_cl * 8] = pack8(P[0][0], P[0][1]);       \
        *(uintx4*)&SA[b][a1_row][a1_cl * 8] = pack8(P[1][0], P[1][1]);       \
        *(uintx4*)&SG[b][w_row][w_cl * 8]   = pack8(P[2][0], P[2][1]);       \
        *(uintx4*)&SU[b][w_row][w_cl * 8]   = pack8(P[3][0], P[3][1]);       \
    } while (0)

#define COMPUTE(b) do {                                                      \
        short8 af[4], gf[2], uf[2];                                          \
        _Pragma("unroll")                                                    \
        for (int m = 0; m < 4; ++m) {                                        \
            const int R = wr * 64 + m * 16 + frow;                           \
            const int p = h ^ (R & 3);                                       \
            af[m] = *(const short8*)&SA[b][R][p * 8];                        \
        }                                                                    \
        _Pragma("unroll")                                                    \
        for (int n = 0; n < 2; ++n) {                                        \
            const int R = wc * 32 + n * 16 + frow;                           \
            const int p = h ^ (R & 3);                                       \
            gf[n] = *(const short8*)&SG[b][R][p * 8];                        \
            uf[n] = *(const short8*)&SU[b][R][p * 8];                        \
        }                                                                    \
        _Pragma("unroll")                                                    \
        for (int m = 0; m < 4; ++m)                                          \
            _Pragma("unroll")                                                \
            for (int n = 0; n < 2; ++n) {                                    \
                accg[m][n] = __builtin_amdgcn_mfma_f32_16x16x32_bf16(        \
                    af[m], gf[n], accg[m][n], 0, 0, 0);                      \
                accu[m][n] = __builtin_amdgcn_mfma_f32_16x16x32_bf16(        \
                    af[m], uf[n], accu[m][n], 0, 0, 0);                      \
            }                                                                \
    } while (0)

#define ENDBAR() do {                                                        \
        asm volatile("s_waitcnt lgkmcnt(0)" ::: "memory");                   \
        __builtin_amdgcn_sched_barrier(0);                                   \
        __builtin_amdgcn_s_barrier();                                        \
    } while (0)

    // prologue: tile 0 -> buf0; tile 1 loads in flight
    ISSUE(0);
    WRITE(0);
    ISSUE(1);
    ENDBAR();

    for (int kt = 0; kt < KT; kt += 2) {
        // iter kt: compute buf0(tile kt); write tile kt+1 -> buf1 (waits its
        // loads, issued one compute-phase ago); issue tile kt+2.
        COMPUTE(0);
        WRITE(1);
        if (kt + 2 < KT) ISSUE(kt + 2);
        ENDBAR();
        // iter kt+1
        COMPUTE(1);
        if (kt + 2 < KT) WRITE(0);
        if (kt + 3 < KT) ISSUE(kt + 3);
        ENDBAR();
    }
#undef ISSUE
#undef WRITE
#undef COMPUTE
#undef ENDBAR

    // Epilogue: silu(g)*u -> bf16. C/D: col=lane&15, row=(lane>>4)*4+reg.
    const int ccol  = lane & 15;
    const int crow0 = (lane >> 4) * 4;
    const size_t hbase = ((size_t)e * NT + (size_t)tm * 128) * NI + ti * 64;
    #pragma unroll
    for (int m = 0; m < 4; ++m)
        #pragma unroll
        for (int n = 0; n < 2; ++n)
            #pragma unroll
            for (int j = 0; j < 4; ++j) {
                const float g = accg[m][n][j];
                const float u = accu[m][n][j];
                const float hh = (g / (1.f + __expf(-g))) * u;
                const int row = wr * 64 + m * 16 + crow0 + j;
                const int col = wc * 32 + n * 16 + ccol;
                hidden[hbase + (size_t)row * NI + col] = f2bf(hh);
            }
}

// ---------------------------------------------------------------------------
// Kernel 2: down projection (unchanged — 2 blocks/CU interleaved, ~715 TF).
// ---------------------------------------------------------------------------
__global__ __launch_bounds__(256, 2) void moe_down(
    const ushort* __restrict__ hidden, const float* __restrict__ down,
    float* __restrict__ out)
{
    __shared__ ushort As[2][128][32];
    __shared__ float  Bs[2][128][32];

    const int bid = blockIdx.x;
    const int wg  = (bid & 7) * (2048 / 8) + (bid >> 3);
    const int e   = wg >> 6;
    const int rem = wg & 63;
    const int tn  = rem & 15;
    const int tm  = rem >> 4;

    const int tid  = threadIdx.x;
    const int lane = tid & 63;
    const int wave = tid >> 6;
    const int wr = wave >> 1, wc = wave & 1;

    const ushort* Ab = hidden + ((size_t)e * NT + (size_t)tm * 128) * NI;
    const float*  Bb = down + (size_t)e * NH * NI + (size_t)(tn * 128) * NI;

    floatx4 acc[4][4];
    #pragma unroll
    for (int m = 0; m < 4; ++m)
        #pragma unroll
        for (int n = 0; n < 4; ++n) acc[m][n] = (floatx4)0.f;

    const int frow = lane & 15;
    const int h    = lane >> 4;
    const int ca   = h ^ (frow & 3);
    const int rb   = frow & 7;
    const int c0   = (2 * h) ^ rb;
    const int c1   = (2 * h + 1) ^ rb;
    const int KT = NI / 32;

#define STAGE_DN(kt, b) do {                                                 \
        const int k0_ = (kt) * 32;                                           \
        _Pragma("unroll")                                                    \
        for (int i = 0; i < 2; ++i) {                                        \
            const int g_ = wave * 2 + i;                                     \
            const int r_ = g_ * 16 + (lane >> 2);                            \
            const int cs_ = (lane & 3) ^ (r_ & 3);                           \
            gl_lds16(Ab + (size_t)r_ * NI + k0_ + cs_ * 8, &As[b][g_ * 16][0]); \
        }                                                                    \
        _Pragma("unroll")                                                    \
        for (int i = 0; i < 4; ++i) {                                        \
            const int g_ = wave * 4 + i;                                     \
            const int r_ = g_ * 8 + (lane >> 3);                             \
            const int cs_ = (lane & 7) ^ (r_ & 7);                           \
            gl_lds16(Bb + (size_t)r_ * NI + k0_ + cs_ * 4, &Bs[b][g_ * 8][0]); \
        }                                                                    \
    } while (0)

    STAGE_DN(0, 0);

    for (int kt = 0; kt < KT; ++kt) {
        const int cur = kt & 1;
        if (kt + 1 < KT) {
            STAGE_DN(kt + 1, cur ^ 1);
            asm volatile("s_waitcnt vmcnt(6)" ::: "memory");
        } else {
            asm volatile("s_waitcnt vmcnt(0)" ::: "memory");
        }
        __builtin_amdgcn_s_barrier();

        short8 af[4], bf[4];
        #pragma unroll
        for (int m = 0; m < 4; ++m) {
            const int R = wr * 64 + m * 16 + frow;
            af[m] = *(const short8*)&As[cur][R][ca * 8];
        }
        #pragma unroll
        for (int n = 0; n < 4; ++n) {
            const int R = wc * 64 + n * 16 + frow;
            bf[n] = frag8(*(const floatx4*)&Bs[cur][R][c0 * 4],
                          *(const floatx4*)&Bs[cur][R][c1 * 4]);
        }
        #pragma unroll
        for (int m = 0; m < 4; ++m)
            #pragma unroll
            for (int n = 0; n < 4; ++n)
                acc[m][n] = __builtin_amdgcn_mfma_f32_16x16x32_bf16(
                    af[m], bf[n], acc[m][n], 0, 0, 0);

        asm volatile("s_waitcnt lgkmcnt(0)" ::: "memory");
        __builtin_amdgcn_sched_barrier(0);
        __builtin_amdgcn_s_barrier();
    }
#undef STAGE_DN

    const int ccol  = lane & 15;
    const int crow0 = (lane >> 4) * 4;
    float* Ob = out + ((size_t)e * NT + (size_t)tm * 128) * NH + tn * 128;
    #pragma unroll
    for (int m = 0; m < 4; ++m)
        #pragma unroll
        for (int n = 0; n < 4; ++n)
            #pragma unroll
            for (int j = 0; j < 4; ++j) {
                const int row = wr * 64 + m * 16 + crow0 + j;
                const int col = wc * 64 + n * 16 + ccol;
                Ob[(size_t)row * NH + col] = acc[m][n][j];
            }
}

extern "C" void kernel_launch(void* const* d_in, const int* in_sizes, int n_in,
                              void* d_out, int out_size, void* d_ws, size_t ws_size,
                              hipStream_t stream) {
    const float* rin  = (const float*)d_in[0];
    const float* gate = (const float*)d_in[1];
    const float* up   = (const float*)d_in[2];
    const float* down = (const float*)d_in[3];
    float* out = (float*)d_out;
    ushort* hidden = (ushort*)d_ws;   // [E,T,I] bf16, 24 MB

    moe_gateup<<<dim3(1536), dim3(256), 0, stream>>>(rin, gate, up, hidden);
    moe_down<<<dim3(2048), dim3(256), 0, stream>>>(hidden, down, out);
}